// Round 12
// baseline (426.456 us; speedup 1.0000x reference)
//
#include <hip/hip_runtime.h>
#include <hip/hip_bf16.h>
#include <cstdint>
#include <type_traits>

#define D_MODEL 2048
#define NH 16
#define HD 128
#define SEQ 2048
#define QKV_LD (3 * D_MODEL) // 6144

typedef __attribute__((ext_vector_type(8))) short short8;
typedef __attribute__((ext_vector_type(4))) float f32x4;
typedef __attribute__((ext_vector_type(16))) float f32x16;

__device__ __forceinline__ ushort f2bf(float f) {
    union { float f; uint32_t u; } c; c.f = f;
    uint32_t u = c.u;
    uint32_t r = (u + 0x7FFFu + ((u >> 16) & 1u)) >> 16;
    return (ushort)r;
}
__device__ __forceinline__ float bf2f(ushort b) {
    union { uint32_t u; float f; } c; c.u = ((uint32_t)b) << 16;
    return c.f;
}

// async global->LDS, 16B per lane. LDS dest = wave-uniform base + lane*16 (HW).
__device__ __forceinline__ void load_lds16(const ushort* g, ushort* l) {
    __builtin_amdgcn_global_load_lds(
        (const __attribute__((address_space(1))) void*)g,
        (__attribute__((address_space(3))) void*)l, 16, 0, 0);
}

#define WAITV(N) asm volatile("s_waitcnt vmcnt(" #N ")" ::: "memory")
#define BARF()   do { __builtin_amdgcn_s_barrier(); \
                      asm volatile("" ::: "memory"); } while (0)
#define PRIO1    __builtin_amdgcn_s_setprio(1)
#define PRIO0    __builtin_amdgcn_s_setprio(0)

// ================= fused prep: rope_table + x->bf16 + W transposes (1 launch) ==========
__device__ __forceinline__ void transpose_body(const float* __restrict__ in,
                                               ushort* __restrict__ out,
                                               int R, int C, int bx, int by, int t,
                                               float (*tile)[33]) {
    int tx = t & 31, ty = t >> 5; // 32 x 8
    int c0 = bx * 32, r0 = by * 32;
    for (int i = 0; i < 4; ++i) {
        int r = r0 + ty + i * 8;
        tile[ty + i * 8][tx] = in[(size_t)r * C + c0 + tx];
    }
    __syncthreads();
    for (int i = 0; i < 4; ++i) {
        int c = c0 + ty + i * 8;
        out[(size_t)c * R + r0 + tx] = f2bf(tile[tx][ty + i * 8]);
    }
}

__global__ void prep_fused(const float* __restrict__ x, ushort* __restrict__ x_bf,
                           const float* __restrict__ Wqkv, ushort* __restrict__ wqkvT,
                           const float* __restrict__ Wo, ushort* __restrict__ woT,
                           float2* __restrict__ rtab) {
    __shared__ float tile[32][33];
    int blk = blockIdx.x;
    int t = threadIdx.x;
    if (blk < 512) {
        // rope cos/sin table: [s][j], same math as original per-element path
        int i = blk * 256 + t; // 0..131071
        int s = i >> 6, j = i & 63;
        float theta = powf(10000.0f, -(float)j * (1.0f / 64.0f));
        float ang = (float)s * theta;
        float sn, cs;
        sincosf(ang, &sn, &cs);
        rtab[i] = make_float2(cs, sn);
    } else if (blk < 8704) {
        // x fp32 -> bf16, 8192 blocks x 256 x float4 = 2097152 exactly
        int idx = (blk - 512) * 256 + t;
        float4 v = ((const float4*)x)[idx];
        ushort4 o;
        o.x = f2bf(v.x); o.y = f2bf(v.y); o.z = f2bf(v.z); o.w = f2bf(v.w);
        ((ushort4*)x_bf)[idx] = o;
    } else if (blk < 20992) {
        // Wqkv [2048][6144] -> wqkvT bf16 [6144][2048]; grid was (192,64)
        int i = blk - 8704;
        transpose_body(Wqkv, wqkvT, 2048, 6144, i % 192, i / 192, t, tile);
    } else {
        // Wo [2048][2048] -> woT bf16; grid was (64,64)
        int i = blk - 20992;
        transpose_body(Wo, woT, 2048, 2048, i & 63, i >> 6, t, tile);
    }
}

// ================= 256 x (128*NHALF) pipelined bf16 GEMM (used for out-proj) ==========
#define B_ROWOFF(L) (NHALF == 2 ? (((L) & 1) * 128 + ((L) >> 1) * 32) : ((L) * 64))
#define STAGE_A(L, T_, B_) load_lds16(Ag + (size_t)(L) * 64 * K + (size_t)(T_) * 64, \
                                      smA + (B_) * 16384 + (L) * 4096 + ldsW)
#define STAGE_B(L, T_, B_) load_lds16(Bg + (size_t)B_ROWOFF(L) * K + (size_t)(T_) * 64, \
                                      smB + (B_) * (8192 * NHALF) + (L) * 4096 + ldsW)
#define READ_A(MH) do { const ushort* _ab = smA + cb * 16384 + aRow + (MH) * 4096; \
    _Pragma("unroll") for (int i_ = 0; i_ < 4; ++i_) { \
        af[i_][0] = *(const short8*)(_ab + i_ * 1024 + pc0); \
        af[i_][1] = *(const short8*)(_ab + i_ * 1024 + pc1); } } while (0)
#define READ_BH(dst, NHh) do { const ushort* _bb = smB + cb * (8192 * NHALF) + (NHh) * 8192 + bRow; \
    _Pragma("unroll") for (int j_ = 0; j_ < 2; ++j_) { \
        dst[j_][0] = *(const short8*)(_bb + j_ * 1024 + pc0); \
        dst[j_][1] = *(const short8*)(_bb + j_ * 1024 + pc1); } } while (0)
#define MFMA_PH(MH, NHh, bf) do { \
    _Pragma("unroll") for (int i_ = 0; i_ < 4; ++i_) \
    _Pragma("unroll") for (int j_ = 0; j_ < 2; ++j_) { \
        acc[(MH) * 4 + i_][(NHh) * 2 + j_] = __builtin_amdgcn_mfma_f32_16x16x32_bf16( \
            af[i_][0], bf[j_][0], acc[(MH) * 4 + i_][(NHh) * 2 + j_], 0, 0, 0); \
        acc[(MH) * 4 + i_][(NHh) * 2 + j_] = __builtin_amdgcn_mfma_f32_16x16x32_bf16( \
            af[i_][1], bf[j_][1], acc[(MH) * 4 + i_][(NHh) * 2 + j_], 0, 0, 0); } } while (0)

template <typename OutT, int NHALF>
__global__ __launch_bounds__(512, 2) void gemm256(
    const ushort* __restrict__ A,   // [M][K] bf16
    const ushort* __restrict__ Bt,  // [N][K] bf16
    const float* __restrict__ bias, // [N]
    OutT* __restrict__ C,           // [M][N]
    int M, int N, int K)
{
    __shared__ __align__(16) ushort sm[32768 + 2 * 8192 * NHALF];
    ushort* smA = sm;
    ushort* smB = sm + 32768;

    int t = threadIdx.x;
    int w = t >> 6, lane = t & 63;
    int lr = lane & 15, lh = lane >> 4;
    int wm_idx = w >> 2, wn_idx = w & 3;
    int m0 = blockIdx.y * 256, n0 = blockIdx.x * (128 * NHALF);

    int srow = t >> 3;
    int scol = ((t & 7) ^ (srow & 7)) << 3;
    const ushort* Ag = A + (size_t)(m0 + srow) * K + scol;
    int bq = (NHALF == 2) ? ((srow >> 5) * 64 + (srow & 31)) : srow;
    const ushort* Bg = Bt + (size_t)(n0 + bq) * K + scol;
    int ldsW = w * 512;

    int pc0 = (lh ^ (lr & 7)) << 3;
    int pc1 = ((4 + lh) ^ (lr & 7)) << 3;
    int aRow = (wm_idx * 128 + lr) * 64;
    int bRow = (wn_idx * 32 + lr) * 64;

    f32x4 acc[8][2 * NHALF];
#pragma unroll
    for (int i = 0; i < 8; ++i)
#pragma unroll
        for (int j = 0; j < 2 * NHALF; ++j) acc[i][j] = (f32x4)0.0f;
    short8 af[4][2], bf0[2][2], bf1[2][2];

    int NT = K >> 6;

    if constexpr (NHALF == 2) {
        STAGE_A(0, 0, 0); STAGE_A(2, 0, 0); STAGE_B(0, 0, 0); STAGE_B(1, 0, 0);
        STAGE_B(2, 0, 0); STAGE_B(3, 0, 0);
        STAGE_A(1, 0, 0); STAGE_A(3, 0, 0);
        WAITV(4);
    } else {
        STAGE_A(0, 0, 0); STAGE_A(2, 0, 0); STAGE_B(0, 0, 0);
        STAGE_B(1, 0, 0); STAGE_A(1, 0, 0); STAGE_A(3, 0, 0);
        WAITV(2);
    }
    BARF();

    for (int T = 0; T < NT; ++T) {
        int cb = T & 1, nb = cb ^ 1;
        bool pf = (T + 1 < NT);
        if constexpr (NHALF == 2) {
            READ_A(0); READ_BH(bf0, 0);
            if (pf) { STAGE_A(0, T + 1, nb); STAGE_A(2, T + 1, nb);
                      STAGE_B(0, T + 1, nb); STAGE_B(1, T + 1, nb); }
            BARF();
            PRIO1; MFMA_PH(0, 0, bf0); PRIO0;
            if (pf) WAITV(6); else WAITV(2);
            BARF();
            READ_BH(bf1, 1);
            if (pf) { STAGE_B(2, T + 1, nb); STAGE_B(3, T + 1, nb); }
            BARF();
            PRIO1; MFMA_PH(0, 1, bf1); PRIO0;
            if (pf) WAITV(6); else WAITV(0);
            BARF();
            READ_A(1);
            if (pf) { STAGE_A(1, T + 1, nb); STAGE_A(3, T + 1, nb); }
            BARF();
            PRIO1; MFMA_PH(1, 1, bf1); MFMA_PH(1, 0, bf0); PRIO0;
            if (pf) WAITV(4);
            BARF();
        } else {
            READ_A(0); READ_BH(bf0, 0);
            if (pf) { STAGE_A(0, T + 1, nb); STAGE_A(2, T + 1, nb); STAGE_B(0, T + 1, nb); }
            BARF();
            PRIO1; MFMA_PH(0, 0, bf0); PRIO0;
            if (pf) WAITV(3); else WAITV(0);
            BARF();
            READ_A(1);
            if (pf) { STAGE_B(1, T + 1, nb); STAGE_A(1, T + 1, nb); STAGE_A(3, T + 1, nb); }
            BARF();
            PRIO1; MFMA_PH(1, 0, bf0); PRIO0;
            if (pf) WAITV(2);
            BARF();
        }
    }

    float bv[2 * NHALF];
#pragma unroll
    for (int jj = 0; jj < 2 * NHALF; ++jj) bv[jj] = bias[n0 + wn_idx * 32 * NHALF + jj * 16 + lr];
#pragma unroll
    for (int ii = 0; ii < 8; ++ii) {
        int row = m0 + wm_idx * 128 + ii * 16 + lh * 4;
#pragma unroll
        for (int jj = 0; jj < 2 * NHALF; ++jj) {
            int col = n0 + wn_idx * 32 * NHALF + jj * 16 + lr;
#pragma unroll
            for (int r = 0; r < 4; ++r) {
                float v = acc[ii][jj][r] + bv[jj];
                if constexpr (std::is_same<OutT, ushort>::value)
                    C[(size_t)(row + r) * N + col] = f2bf(v);
                else
                    C[(size_t)(row + r) * N + col] = v;
            }
        }
    }
}

// ================= 128 x 384 pipelined bf16 GEMM (QKV projection) =================
// Grid (16,32)=512 blocks = exactly 2 full rounds. See R4 notes; unchanged.
#define STAGE_A3(L, T_, B_) load_lds16(Ag + (size_t)(L) * 64 * K + (size_t)(T_) * 64, \
                                       smA + (B_) * 8192 + (L) * 4096 + ldsW)
#define STAGE_B3(L, T_, B_) load_lds16(Bg + (size_t)((((L) & 1) * 2 + wnp) * 96 + ((L) >> 1) * 32 + rb) * K + (size_t)(T_) * 64, \
                                       smB + (B_) * 24576 + (L) * 4096 + ldsW)
#define READ_A3() do { const ushort* _ab = smA + cb * 8192 + aRow; \
    _Pragma("unroll") for (int i_ = 0; i_ < 4; ++i_) { \
        af[i_][0] = *(const short8*)(_ab + i_ * 1024 + pc0); \
        af[i_][1] = *(const short8*)(_ab + i_ * 1024 + pc1); } } while (0)
#define READ_B3(H) do { const ushort* _bb = smB + cb * 24576 + (H) * 8192 + bRow; \
    _Pragma("unroll") for (int j_ = 0; j_ < 2; ++j_) { \
        bfr[j_][0] = *(const short8*)(_bb + j_ * 1024 + pc0); \
        bfr[j_][1] = *(const short8*)(_bb + j_ * 1024 + pc1); } } while (0)
#define MFMA_P3(H) do { \
    _Pragma("unroll") for (int i_ = 0; i_ < 4; ++i_) \
    _Pragma("unroll") for (int j_ = 0; j_ < 2; ++j_) { \
        acc[i_][(H) * 2 + j_] = __builtin_amdgcn_mfma_f32_16x16x32_bf16( \
            af[i_][0], bfr[j_][0], acc[i_][(H) * 2 + j_], 0, 0, 0); \
        acc[i_][(H) * 2 + j_] = __builtin_amdgcn_mfma_f32_16x16x32_bf16( \
            af[i_][1], bfr[j_][1], acc[i_][(H) * 2 + j_], 0, 0, 0); } } while (0)

__global__ __launch_bounds__(512, 2) void gemm384(
    const ushort* __restrict__ A,   // [M][K] bf16
    const ushort* __restrict__ Bt,  // [N][K] bf16
    const float* __restrict__ bias, // [N]
    ushort* __restrict__ C,         // [M][N] bf16
    int M, int N, int K)
{
    __shared__ __align__(16) ushort sm[65536]; // A [0,16384), B [16384,65536)
    ushort* smA = sm;
    ushort* smB = sm + 16384;

    int t = threadIdx.x;
    int w = t >> 6, lane = t & 63;
    int lr = lane & 15, lh = lane >> 4;
    int wm_idx = w >> 2, wn_idx = w & 3;    // 2 x 4 wave grid, per-wave 64 x 96
    int m0 = blockIdx.y * 128, n0 = blockIdx.x * 384;

    int srow = t >> 3;                       // 0..63
    int scol = ((t & 7) ^ (srow & 7)) << 3;  // pre-swizzled source chunk
    const ushort* Ag = A + (size_t)(m0 + srow) * K + scol;
    const ushort* Bg = Bt + (size_t)n0 * K + scol;
    int wnp = srow >> 5;                     // B perm helpers
    int rb = srow & 31;
    int ldsW = w * 512;

    int pc0 = (lh ^ (lr & 7)) << 3;
    int pc1 = ((4 + lh) ^ (lr & 7)) << 3;
    int aRow = (wm_idx * 64 + lr) * 64;
    int bRow = (wn_idx * 32 + lr) * 64;

    f32x4 acc[4][6];
#pragma unroll
    for (int i = 0; i < 4; ++i)
#pragma unroll
        for (int j = 0; j < 6; ++j) acc[i][j] = (f32x4)0.0f;
    short8 af[4][2], bfr[2][2];

    int NT = K >> 6;

    STAGE_A3(0, 0, 0); STAGE_A3(1, 0, 0); STAGE_B3(0, 0, 0); STAGE_B3(1, 0, 0);
    STAGE_B3(2, 0, 0); STAGE_B3(3, 0, 0); STAGE_B3(4, 0, 0); STAGE_B3(5, 0, 0);
    WAITV(4);
    BARF();

    for (int T = 0; T < NT; ++T) {
        int cb = T & 1, nb = cb ^ 1;
        bool pf = (T + 1 < NT);
        // ---- P1: A x B-half0 ----
        READ_A3(); READ_B3(0);
        if (pf) { STAGE_A3(0, T + 1, nb); STAGE_A3(1, T + 1, nb); STAGE_B3(0, T + 1, nb); }
        BARF();
        PRIO1; MFMA_P3(0); PRIO0;
        if (pf) WAITV(5); else WAITV(2);
        BARF();
        // ---- P2: A x B-half1 (A cached) ----
        READ_B3(1);
        if (pf) { STAGE_B3(1, T + 1, nb); STAGE_B3(2, T + 1, nb); STAGE_B3(3, T + 1, nb); }
        BARF();
        PRIO1; MFMA_P3(1); PRIO0;
        if (pf) WAITV(6); else WAITV(0);
        BARF();
        // ---- P3: A x B-half2 ----
        READ_B3(2);
        if (pf) { STAGE_B3(4, T + 1, nb); STAGE_B3(5, T + 1, nb); }
        BARF();
        PRIO1; MFMA_P3(2); PRIO0;
        if (pf) WAITV(4);
        BARF();
    }

    float bv[6];
#pragma unroll
    for (int jj = 0; jj < 6; ++jj) bv[jj] = bias[n0 + wn_idx * 96 + jj * 16 + lr];
#pragma unroll
    for (int ii = 0; ii < 4; ++ii) {
        int row = m0 + wm_idx * 64 + ii * 16 + lh * 4;
#pragma unroll
        for (int jj = 0; jj < 6; ++jj) {
            int col = n0 + wn_idx * 96 + jj * 16 + lr;
#pragma unroll
            for (int r = 0; r < 4; ++r) {
                float v = acc[ii][jj][r] + bv[jj];
                C[(size_t)(row + r) * N + col] = f2bf(v);
            }
        }
    }
}

// ================= fused RoPE q/k + V transpose (1 launch) =================
// Q pre-scale now folds log2(e) so attention can use exp2 directly:
// S' = S*log2e  =>  exp2(S' - m') == exp(S - m) exactly (real algebra).
__global__ void rope_v_fused(const ushort* __restrict__ qkv, const float2* __restrict__ tab,
                             ushort* __restrict__ Qb, ushort* __restrict__ Kb,
                             ushort* __restrict__ Vt) {
    __shared__ ushort tile[32][33];
    int blk = blockIdx.x;
    int t = threadIdx.x;
    if (blk < 32768) {
        // RoPE + cast + reshape q,k; Q pre-scaled by (1/sqrt(HD)) * log2(e)
        int wv = blk * 4 + (t >> 6); // 0..131071
        int j = t & 63;
        int bs = wv >> 5;
        int rem = wv & 31;
        int which = rem >> 4;  // 0=q, 1=k
        int h = rem & 15;
        int s = bs & 2047;
        int b = bs >> 11;
        size_t src = (size_t)bs * QKV_LD + which * D_MODEL + h * HD;
        uint32_t pr = *(const uint32_t*)(qkv + src + 2 * j);
        float x1 = bf2f((ushort)(pr & 0xffff));
        float x2 = bf2f((ushort)(pr >> 16));
        float2 cspair = tab[(s << 6) + j];
        float cs = cspair.x, sn = cspair.y;
        float sc = which ? 1.0f : 0.08838834764831845f * 1.4426950408889634f;
        float o1 = (x1 * cs - x2 * sn) * sc;
        float o2 = (x1 * sn + x2 * cs) * sc;
        ushort* dst = which ? Kb : Qb;
        size_t obase = ((size_t)(b * NH + h) * SEQ + s) * HD;
        dst[obase + j] = f2bf(o1);
        dst[obase + 64 + j] = f2bf(o2);
    } else {
        // V transpose -> Vt [bh][d=128][s=2048]; original grid (64,4,32)
        int i = blk - 32768;
        int bx = i & 63, by = (i >> 6) & 3, bz = i >> 8;
        int tx = t & 31, ty = t >> 5; // 32 x 8
        int s0 = bx * 32;
        int d0 = by * 32;
        int bh = bz;
        int b = bh >> 4, h = bh & 15;
        for (int k = 0; k < 4; ++k) {
            int s = s0 + ty + k * 8;
            tile[ty + k * 8][tx] = qkv[((size_t)(b * SEQ + s)) * QKV_LD + 2 * D_MODEL + h * HD + d0 + tx];
        }
        __syncthreads();
        for (int k = 0; k < 4; ++k) {
            int d = d0 + ty + k * 8;
            Vt[((size_t)bh * HD + d) * SEQ + s0 + tx] = tile[tx][ty + k * 8];
        }
    }
}

// ---------------- MFMA flash attention ----------------
// R5-proven structure + two pressure-REMOVING deltas:
//  (a) K/V staging via global_load_lds: attn phys LDS layout is linear in f=c2*256+t
//      (K: f*16B = r*256 + cphys*16; V: f*16B = d*128 + cphys*16), so DMA with
//      inverse-swizzled SOURCE (rule 21) replaces 8 VGPR round-trips + 8 ds_writes.
//  (b) softmax in exp2 domain (log2e folded into Q scale upstream): bare v_exp per P.
// XCD-aware work swizzle (bijective, 512%8==0): all 16 q-tiles of each bh on one XCD.
__global__ __launch_bounds__(256) void attn_mfma(const ushort* __restrict__ Qb,
                                                 const ushort* __restrict__ Kb,
                                                 const ushort* __restrict__ Vt,
                                                 ushort* __restrict__ ctx) {
    __shared__ __align__(16) ushort smem[25600]; // Ks[0,8192) Vts[8192,16384) Ps[16384,25600)
    ushort* Ks = smem;          // [64][128], 16B chunks swizzled: phys p = logical ^ (row&15)
    ushort* Vts = smem + 8192;  // [128][64], 16B chunks swizzled: phys p = logical ^ (row&7)
    ushort* Ps = smem + 16384;  // [128][72] (pad 8 => 144B rows, 16B aligned)

    int t = threadIdx.x;
    int w = t >> 6, l = t & 63;
    int l31 = l & 31, g = l >> 5;
    int flat = blockIdx.y * 16 + blockIdx.x;    // launched id, 0..511
    int wid = (flat & 7) * 64 + (flat >> 3);    // work id, XCD-grouped by bh
    int q0 = (wid & 15) * 128;
    int bh = wid >> 4;
    int b = bh >> 4, h = bh & 15;

    int qrow = q0 + w * 32 + l31;
    const ushort* Qg = Qb + ((size_t)bh * SEQ + qrow) * HD;
    short8 qf[8];
#pragma unroll
    for (int kc = 0; kc < 8; kc++)
        qf[kc] = *(const short8*)(Qg + kc * 16 + g * 8);

    f32x16 O[4];
#pragma unroll
    for (int di = 0; di < 4; di++) O[di] = (f32x16)0.0f;
    float m_run = -INFINITY, l_run = 0.0f;

    const ushort* KgB = Kb + (size_t)bh * SEQ * HD;
    const ushort* VtB = Vt + (size_t)bh * HD * SEQ;

    for (int k0 = 0; k0 < SEQ; k0 += 64) {
        __syncthreads();
        // K: 4 x DMA, linear LDS dest (f*16B), source col = (f&15)^(r&15)
#pragma unroll
        for (int c2 = 0; c2 < 4; c2++) {
            int f = c2 * 256 + t;
            int r = f >> 4;
            int cl = (f & 15) ^ (r & 15);
            load_lds16(KgB + (size_t)(k0 + r) * HD + cl * 8, Ks + c2 * 2048 + w * 512);
        }
        // V: 4 x DMA, linear LDS dest, source col = (f&7)^(d&7)
#pragma unroll
        for (int c2 = 0; c2 < 4; c2++) {
            int f = c2 * 256 + t;
            int d = f >> 3;
            int cl = (f & 7) ^ (d & 7);
            load_lds16(VtB + (size_t)d * SEQ + k0 + cl * 8, Vts + c2 * 2048 + w * 512);
        }
        WAITV(0);
        __syncthreads();

        // S^T = K . Q^T : per wave [64 keys][32 q] as 2 tiles of 32x32
        f32x16 St[2];
        St[0] = (f32x16)0.0f;
        St[1] = (f32x16)0.0f;
#pragma unroll
        for (int ki = 0; ki < 2; ki++) {
            int row = ki * 32 + l31;
#pragma unroll
            for (int kc = 0; kc < 8; kc++) {
                int cp = (kc * 2 + g) ^ (row & 15);
                short8 a = *(const short8*)(Ks + row * 128 + cp * 8);
                St[ki] = __builtin_amdgcn_mfma_f32_32x32x16_bf16(a, qf[kc], St[ki], 0, 0, 0);
            }
        }

        // online softmax in exp2 domain: this lane's q = q0+w*32+l31
        float mx = -INFINITY;
#pragma unroll
        for (int ki = 0; ki < 2; ki++)
#pragma unroll
            for (int r = 0; r < 16; r++) mx = fmaxf(mx, St[ki][r]);
        mx = fmaxf(mx, __shfl_xor(mx, 32));
        float mn = fmaxf(m_run, mx);
        float alpha = exp2f(m_run - mn);
        m_run = mn;
        float psum = 0.0f;
#pragma unroll
        for (int ki = 0; ki < 2; ki++)
#pragma unroll
            for (int r = 0; r < 16; r++) {
                float p = exp2f(St[ki][r] - mn);
                St[ki][r] = p;
                psum += p;
            }
        psum += __shfl_xor(psum, 32);
        l_run = l_run * alpha + psum;
#pragma unroll
        for (int di = 0; di < 4; di++)
#pragma unroll
            for (int r = 0; r < 16; r++) O[di][r] *= alpha;

        // P (bf16) -> LDS, wave-private rows; reg-quads = 4 consecutive keys => b64 writes
        {
            int qloc = w * 32 + l31;
            ushort* Pr = Ps + qloc * 72;
#pragma unroll
            for (int ki = 0; ki < 2; ki++)
#pragma unroll
                for (int u = 0; u < 4; u++) {
                    ushort4 pk;
                    pk.x = f2bf(St[ki][4 * u + 0]);
                    pk.y = f2bf(St[ki][4 * u + 1]);
                    pk.z = f2bf(St[ki][4 * u + 2]);
                    pk.w = f2bf(St[ki][4 * u + 3]);
                    *(ushort4*)(Pr + ki * 32 + 8 * u + 4 * g) = pk;
                }
        }

        // O^T += V^T . P^T : per wave [128 d][32 q] as 4 tiles of 32x32
        {
            int qloc = w * 32 + l31;
            short8 pb[4];
#pragma unroll
            for (int kc = 0; kc < 4; kc++)
                pb[kc] = *(const short8*)(Ps + qloc * 72 + kc * 16 + g * 8);
#pragma unroll
            for (int di = 0; di < 4; di++) {
                int d = di * 32 + l31;
#pragma unroll
                for (int kc = 0; kc < 4; kc++) {
                    int cp = (kc * 2 + g) ^ (d & 7);
                    short8 va = *(const short8*)(Vts + d * 64 + cp * 8);
                    O[di] = __builtin_amdgcn_mfma_f32_32x32x16_bf16(va, pb[kc], O[di], 0, 0, 0);
                }
            }
        }
    }

    __syncthreads();
    float inv = 1.0f / l_run;
    ushort* ob = smem; // [128][128] rows = block-local q
    {
        int qloc = w * 32 + l31;
        ushort* orow = ob + qloc * 128;
#pragma unroll
        for (int di = 0; di < 4; di++)
#pragma unroll
            for (int u = 0; u < 4; u++) {
                ushort4 pk;
                pk.x = f2bf(O[di][4 * u + 0] * inv);
                pk.y = f2bf(O[di][4 * u + 1] * inv);
                pk.z = f2bf(O[di][4 * u + 2] * inv);
                pk.w = f2bf(O[di][4 * u + 3] * inv);
                *(ushort4*)(orow + di * 32 + 8 * u + 4 * g) = pk;
            }
    }
#pragma unroll
    for (int p = 0; p < 8; p++) {
        int qloc = w * 32 + p * 4 + (l >> 4);
        int c16 = l & 15;
        uint4 v = *(const uint4*)(ob + qloc * 128 + c16 * 8);
        size_t tok = (size_t)b * SEQ + q0 + qloc;
        *(uint4*)(ctx + tok * D_MODEL + h * HD + c16 * 8) = v;
    }
}

extern "C" void kernel_launch(void* const* d_in, const int* in_sizes, int n_in,
                              void* d_out, int out_size, void* d_ws, size_t ws_size,
                              hipStream_t stream) {
    const float* x    = (const float*)d_in[0];
    const float* Wqkv = (const float*)d_in[1];
    const float* bqkv = (const float*)d_in[2];
    const float* Wo   = (const float*)d_in[3];
    const float* bo   = (const float*)d_in[4];
    float* out = (float*)d_out;

    char* ws = (char*)d_ws;
    ushort* x_bf   = (ushort*)(ws);                  // 16 MB [0,16M)
    ushort* wqkvT  = (ushort*)(ws + 16777216);       // 24 MB
    ushort* woT    = (ushort*)(ws + 41943040);       //  8 MB
    ushort* qkv_bf = (ushort*)(ws + 50331648);       // 48 MB: [4096][6144] bf16
    ushort* Qb     = (ushort*)(ws + 100663296);      // 16 MB: [32][2048][128] bf16
    ushort* Kb     = (ushort*)(ws + 117440512);      // 16 MB
    ushort* VtG    = (ushort*)(ws + 134217728);      // 16 MB: [32][128][2048] bf16
    ushort* ctx    = (ushort*)(ws + 150994944);      // 16 MB -> total 160 MB
    // rope table overlaps ctx region (1 MB): consumed by rope_v_fused BEFORE attn writes ctx.
    float2* rtab   = (float2*)(ws + 150994944);

    // 1) fused prep: rope table + x->bf16 + Wqkv^T + Wo^T
    prep_fused<<<25088, 256, 0, stream>>>(x, x_bf, Wqkv, wqkvT, Wo, woT, rtab);
    // 2) qkv = x @ Wqkv + bqkv -> bf16 (128x384, 512 blocks = 2 exact rounds)
    gemm384<<<dim3(16, 32), 512, 0, stream>>>(x_bf, wqkvT, bqkv, qkv_bf, 4096, 6144, 2048);
    // 3) fused RoPE q/k (log2e-folded Q scale) + V transpose
    rope_v_fused<<<40960, 256, 0, stream>>>(qkv_bf, rtab, Qb, Kb, VtG);
    // 4) MFMA flash attention -> ctx bf16 (XCD-swizzled, DMA-staged, exp2 softmax)
    attn_mfma<<<dim3(16, 32), 256, 0, stream>>>(Qb, Kb, VtG, ctx);
    // 5) out = ctx @ Wo + bo (256x128, 256 blocks = full machine)
    gemm256<float, 1><<<dim3(16, 16), 512, 0, stream>>>(ctx, woT, bo, out, 4096, 2048, 2048);
}

// Round 13
// 402.795 us; speedup vs baseline: 1.0587x; 1.0587x over previous
//
#include <hip/hip_runtime.h>
#include <hip/hip_bf16.h>
#include <cstdint>
#include <type_traits>

#define D_MODEL 2048
#define NH 16
#define HD 128
#define SEQ 2048
#define QKV_LD (3 * D_MODEL) // 6144

typedef __attribute__((ext_vector_type(8))) short short8;
typedef __attribute__((ext_vector_type(4))) float f32x4;
typedef __attribute__((ext_vector_type(16))) float f32x16;

__device__ __forceinline__ ushort f2bf(float f) {
    union { float f; uint32_t u; } c; c.f = f;
    uint32_t u = c.u;
    uint32_t r = (u + 0x7FFFu + ((u >> 16) & 1u)) >> 16;
    return (ushort)r;
}
__device__ __forceinline__ float bf2f(ushort b) {
    union { uint32_t u; float f; } c; c.u = ((uint32_t)b) << 16;
    return c.f;
}

// async global->LDS, 16B per lane. LDS dest = wave-uniform base + lane*16 (HW).
__device__ __forceinline__ void load_lds16(const ushort* g, ushort* l) {
    __builtin_amdgcn_global_load_lds(
        (const __attribute__((address_space(1))) void*)g,
        (__attribute__((address_space(3))) void*)l, 16, 0, 0);
}

#define WAITV(N) asm volatile("s_waitcnt vmcnt(" #N ")" ::: "memory")
#define BARF()   do { __builtin_amdgcn_s_barrier(); \
                      asm volatile("" ::: "memory"); } while (0)
#define PRIO1    __builtin_amdgcn_s_setprio(1)
#define PRIO0    __builtin_amdgcn_s_setprio(0)

// ================= fused prep: rope_table + x->bf16 + W transposes (1 launch) ==========
__device__ __forceinline__ void transpose_body(const float* __restrict__ in,
                                               ushort* __restrict__ out,
                                               int R, int C, int bx, int by, int t,
                                               float (*tile)[33]) {
    int tx = t & 31, ty = t >> 5; // 32 x 8
    int c0 = bx * 32, r0 = by * 32;
    for (int i = 0; i < 4; ++i) {
        int r = r0 + ty + i * 8;
        tile[ty + i * 8][tx] = in[(size_t)r * C + c0 + tx];
    }
    __syncthreads();
    for (int i = 0; i < 4; ++i) {
        int c = c0 + ty + i * 8;
        out[(size_t)c * R + r0 + tx] = f2bf(tile[tx][ty + i * 8]);
    }
}

__global__ void prep_fused(const float* __restrict__ x, ushort* __restrict__ x_bf,
                           const float* __restrict__ Wqkv, ushort* __restrict__ wqkvT,
                           const float* __restrict__ Wo, ushort* __restrict__ woT,
                           float2* __restrict__ rtab) {
    __shared__ float tile[32][33];
    int blk = blockIdx.x;
    int t = threadIdx.x;
    if (blk < 512) {
        // rope cos/sin table: [s][j], same math as original per-element path
        int i = blk * 256 + t; // 0..131071
        int s = i >> 6, j = i & 63;
        float theta = powf(10000.0f, -(float)j * (1.0f / 64.0f));
        float ang = (float)s * theta;
        float sn, cs;
        sincosf(ang, &sn, &cs);
        rtab[i] = make_float2(cs, sn);
    } else if (blk < 8704) {
        // x fp32 -> bf16, 8192 blocks x 256 x float4 = 2097152 exactly
        int idx = (blk - 512) * 256 + t;
        float4 v = ((const float4*)x)[idx];
        ushort4 o;
        o.x = f2bf(v.x); o.y = f2bf(v.y); o.z = f2bf(v.z); o.w = f2bf(v.w);
        ((ushort4*)x_bf)[idx] = o;
    } else if (blk < 20992) {
        // Wqkv [2048][6144] -> wqkvT bf16 [6144][2048]; grid was (192,64)
        int i = blk - 8704;
        transpose_body(Wqkv, wqkvT, 2048, 6144, i % 192, i / 192, t, tile);
    } else {
        // Wo [2048][2048] -> woT bf16; grid was (64,64)
        int i = blk - 20992;
        transpose_body(Wo, woT, 2048, 2048, i & 63, i >> 6, t, tile);
    }
}

// ================= 256 x (128*NHALF) pipelined bf16 GEMM (used for out-proj) ==========
#define B_ROWOFF(L) (NHALF == 2 ? (((L) & 1) * 128 + ((L) >> 1) * 32) : ((L) * 64))
#define STAGE_A(L, T_, B_) load_lds16(Ag + (size_t)(L) * 64 * K + (size_t)(T_) * 64, \
                                      smA + (B_) * 16384 + (L) * 4096 + ldsW)
#define STAGE_B(L, T_, B_) load_lds16(Bg + (size_t)B_ROWOFF(L) * K + (size_t)(T_) * 64, \
                                      smB + (B_) * (8192 * NHALF) + (L) * 4096 + ldsW)
#define READ_A(MH) do { const ushort* _ab = smA + cb * 16384 + aRow + (MH) * 4096; \
    _Pragma("unroll") for (int i_ = 0; i_ < 4; ++i_) { \
        af[i_][0] = *(const short8*)(_ab + i_ * 1024 + pc0); \
        af[i_][1] = *(const short8*)(_ab + i_ * 1024 + pc1); } } while (0)
#define READ_BH(dst, NHh) do { const ushort* _bb = smB + cb * (8192 * NHALF) + (NHh) * 8192 + bRow; \
    _Pragma("unroll") for (int j_ = 0; j_ < 2; ++j_) { \
        dst[j_][0] = *(const short8*)(_bb + j_ * 1024 + pc0); \
        dst[j_][1] = *(const short8*)(_bb + j_ * 1024 + pc1); } } while (0)
#define MFMA_PH(MH, NHh, bf) do { \
    _Pragma("unroll") for (int i_ = 0; i_ < 4; ++i_) \
    _Pragma("unroll") for (int j_ = 0; j_ < 2; ++j_) { \
        acc[(MH) * 4 + i_][(NHh) * 2 + j_] = __builtin_amdgcn_mfma_f32_16x16x32_bf16( \
            af[i_][0], bf[j_][0], acc[(MH) * 4 + i_][(NHh) * 2 + j_], 0, 0, 0); \
        acc[(MH) * 4 + i_][(NHh) * 2 + j_] = __builtin_amdgcn_mfma_f32_16x16x32_bf16( \
            af[i_][1], bf[j_][1], acc[(MH) * 4 + i_][(NHh) * 2 + j_], 0, 0, 0); } } while (0)

template <typename OutT, int NHALF>
__global__ __launch_bounds__(512, 2) void gemm256(
    const ushort* __restrict__ A,   // [M][K] bf16
    const ushort* __restrict__ Bt,  // [N][K] bf16
    const float* __restrict__ bias, // [N]
    OutT* __restrict__ C,           // [M][N]
    int M, int N, int K)
{
    __shared__ __align__(16) ushort sm[32768 + 2 * 8192 * NHALF];
    ushort* smA = sm;
    ushort* smB = sm + 32768;

    int t = threadIdx.x;
    int w = t >> 6, lane = t & 63;
    int lr = lane & 15, lh = lane >> 4;
    int wm_idx = w >> 2, wn_idx = w & 3;
    int m0 = blockIdx.y * 256, n0 = blockIdx.x * (128 * NHALF);

    int srow = t >> 3;
    int scol = ((t & 7) ^ (srow & 7)) << 3;
    const ushort* Ag = A + (size_t)(m0 + srow) * K + scol;
    int bq = (NHALF == 2) ? ((srow >> 5) * 64 + (srow & 31)) : srow;
    const ushort* Bg = Bt + (size_t)(n0 + bq) * K + scol;
    int ldsW = w * 512;

    int pc0 = (lh ^ (lr & 7)) << 3;
    int pc1 = ((4 + lh) ^ (lr & 7)) << 3;
    int aRow = (wm_idx * 128 + lr) * 64;
    int bRow = (wn_idx * 32 + lr) * 64;

    f32x4 acc[8][2 * NHALF];
#pragma unroll
    for (int i = 0; i < 8; ++i)
#pragma unroll
        for (int j = 0; j < 2 * NHALF; ++j) acc[i][j] = (f32x4)0.0f;
    short8 af[4][2], bf0[2][2], bf1[2][2];

    int NT = K >> 6;

    if constexpr (NHALF == 2) {
        STAGE_A(0, 0, 0); STAGE_A(2, 0, 0); STAGE_B(0, 0, 0); STAGE_B(1, 0, 0);
        STAGE_B(2, 0, 0); STAGE_B(3, 0, 0);
        STAGE_A(1, 0, 0); STAGE_A(3, 0, 0);
        WAITV(4);
    } else {
        STAGE_A(0, 0, 0); STAGE_A(2, 0, 0); STAGE_B(0, 0, 0);
        STAGE_B(1, 0, 0); STAGE_A(1, 0, 0); STAGE_A(3, 0, 0);
        WAITV(2);
    }
    BARF();

    for (int T = 0; T < NT; ++T) {
        int cb = T & 1, nb = cb ^ 1;
        bool pf = (T + 1 < NT);
        if constexpr (NHALF == 2) {
            READ_A(0); READ_BH(bf0, 0);
            if (pf) { STAGE_A(0, T + 1, nb); STAGE_A(2, T + 1, nb);
                      STAGE_B(0, T + 1, nb); STAGE_B(1, T + 1, nb); }
            BARF();
            PRIO1; MFMA_PH(0, 0, bf0); PRIO0;
            if (pf) WAITV(6); else WAITV(2);
            BARF();
            READ_BH(bf1, 1);
            if (pf) { STAGE_B(2, T + 1, nb); STAGE_B(3, T + 1, nb); }
            BARF();
            PRIO1; MFMA_PH(0, 1, bf1); PRIO0;
            if (pf) WAITV(6); else WAITV(0);
            BARF();
            READ_A(1);
            if (pf) { STAGE_A(1, T + 1, nb); STAGE_A(3, T + 1, nb); }
            BARF();
            PRIO1; MFMA_PH(1, 1, bf1); MFMA_PH(1, 0, bf0); PRIO0;
            if (pf) WAITV(4);
            BARF();
        } else {
            READ_A(0); READ_BH(bf0, 0);
            if (pf) { STAGE_A(0, T + 1, nb); STAGE_A(2, T + 1, nb); STAGE_B(0, T + 1, nb); }
            BARF();
            PRIO1; MFMA_PH(0, 0, bf0); PRIO0;
            if (pf) WAITV(3); else WAITV(0);
            BARF();
            READ_A(1);
            if (pf) { STAGE_B(1, T + 1, nb); STAGE_A(1, T + 1, nb); STAGE_A(3, T + 1, nb); }
            BARF();
            PRIO1; MFMA_PH(1, 0, bf0); PRIO0;
            if (pf) WAITV(2);
            BARF();
        }
    }

    float bv[2 * NHALF];
#pragma unroll
    for (int jj = 0; jj < 2 * NHALF; ++jj) bv[jj] = bias[n0 + wn_idx * 32 * NHALF + jj * 16 + lr];
#pragma unroll
    for (int ii = 0; ii < 8; ++ii) {
        int row = m0 + wm_idx * 128 + ii * 16 + lh * 4;
#pragma unroll
        for (int jj = 0; jj < 2 * NHALF; ++jj) {
            int col = n0 + wn_idx * 32 * NHALF + jj * 16 + lr;
#pragma unroll
            for (int r = 0; r < 4; ++r) {
                float v = acc[ii][jj][r] + bv[jj];
                if constexpr (std::is_same<OutT, ushort>::value)
                    C[(size_t)(row + r) * N + col] = f2bf(v);
                else
                    C[(size_t)(row + r) * N + col] = v;
            }
        }
    }
}

// ================= 128 x 384 pipelined bf16 GEMM (QKV projection) =================
// Grid (16,32)=512 blocks = exactly 2 full rounds. See R4 notes; unchanged.
#define STAGE_A3(L, T_, B_) load_lds16(Ag + (size_t)(L) * 64 * K + (size_t)(T_) * 64, \
                                       smA + (B_) * 8192 + (L) * 4096 + ldsW)
#define STAGE_B3(L, T_, B_) load_lds16(Bg + (size_t)((((L) & 1) * 2 + wnp) * 96 + ((L) >> 1) * 32 + rb) * K + (size_t)(T_) * 64, \
                                       smB + (B_) * 24576 + (L) * 4096 + ldsW)
#define READ_A3() do { const ushort* _ab = smA + cb * 8192 + aRow; \
    _Pragma("unroll") for (int i_ = 0; i_ < 4; ++i_) { \
        af[i_][0] = *(const short8*)(_ab + i_ * 1024 + pc0); \
        af[i_][1] = *(const short8*)(_ab + i_ * 1024 + pc1); } } while (0)
#define READ_B3(H) do { const ushort* _bb = smB + cb * 24576 + (H) * 8192 + bRow; \
    _Pragma("unroll") for (int j_ = 0; j_ < 2; ++j_) { \
        bfr[j_][0] = *(const short8*)(_bb + j_ * 1024 + pc0); \
        bfr[j_][1] = *(const short8*)(_bb + j_ * 1024 + pc1); } } while (0)
#define MFMA_P3(H) do { \
    _Pragma("unroll") for (int i_ = 0; i_ < 4; ++i_) \
    _Pragma("unroll") for (int j_ = 0; j_ < 2; ++j_) { \
        acc[i_][(H) * 2 + j_] = __builtin_amdgcn_mfma_f32_16x16x32_bf16( \
            af[i_][0], bfr[j_][0], acc[i_][(H) * 2 + j_], 0, 0, 0); \
        acc[i_][(H) * 2 + j_] = __builtin_amdgcn_mfma_f32_16x16x32_bf16( \
            af[i_][1], bfr[j_][1], acc[i_][(H) * 2 + j_], 0, 0, 0); } } while (0)

__global__ __launch_bounds__(512, 2) void gemm384(
    const ushort* __restrict__ A,   // [M][K] bf16
    const ushort* __restrict__ Bt,  // [N][K] bf16
    const float* __restrict__ bias, // [N]
    ushort* __restrict__ C,         // [M][N] bf16
    int M, int N, int K)
{
    __shared__ __align__(16) ushort sm[65536]; // A [0,16384), B [16384,65536)
    ushort* smA = sm;
    ushort* smB = sm + 16384;

    int t = threadIdx.x;
    int w = t >> 6, lane = t & 63;
    int lr = lane & 15, lh = lane >> 4;
    int wm_idx = w >> 2, wn_idx = w & 3;    // 2 x 4 wave grid, per-wave 64 x 96
    int m0 = blockIdx.y * 128, n0 = blockIdx.x * 384;

    int srow = t >> 3;                       // 0..63
    int scol = ((t & 7) ^ (srow & 7)) << 3;  // pre-swizzled source chunk
    const ushort* Ag = A + (size_t)(m0 + srow) * K + scol;
    const ushort* Bg = Bt + (size_t)n0 * K + scol;
    int wnp = srow >> 5;                     // B perm helpers
    int rb = srow & 31;
    int ldsW = w * 512;

    int pc0 = (lh ^ (lr & 7)) << 3;
    int pc1 = ((4 + lh) ^ (lr & 7)) << 3;
    int aRow = (wm_idx * 64 + lr) * 64;
    int bRow = (wn_idx * 32 + lr) * 64;

    f32x4 acc[4][6];
#pragma unroll
    for (int i = 0; i < 4; ++i)
#pragma unroll
        for (int j = 0; j < 6; ++j) acc[i][j] = (f32x4)0.0f;
    short8 af[4][2], bfr[2][2];

    int NT = K >> 6;

    STAGE_A3(0, 0, 0); STAGE_A3(1, 0, 0); STAGE_B3(0, 0, 0); STAGE_B3(1, 0, 0);
    STAGE_B3(2, 0, 0); STAGE_B3(3, 0, 0); STAGE_B3(4, 0, 0); STAGE_B3(5, 0, 0);
    WAITV(4);
    BARF();

    for (int T = 0; T < NT; ++T) {
        int cb = T & 1, nb = cb ^ 1;
        bool pf = (T + 1 < NT);
        // ---- P1: A x B-half0 ----
        READ_A3(); READ_B3(0);
        if (pf) { STAGE_A3(0, T + 1, nb); STAGE_A3(1, T + 1, nb); STAGE_B3(0, T + 1, nb); }
        BARF();
        PRIO1; MFMA_P3(0); PRIO0;
        if (pf) WAITV(5); else WAITV(2);
        BARF();
        // ---- P2: A x B-half1 (A cached) ----
        READ_B3(1);
        if (pf) { STAGE_B3(1, T + 1, nb); STAGE_B3(2, T + 1, nb); STAGE_B3(3, T + 1, nb); }
        BARF();
        PRIO1; MFMA_P3(1); PRIO0;
        if (pf) WAITV(6); else WAITV(0);
        BARF();
        // ---- P3: A x B-half2 ----
        READ_B3(2);
        if (pf) { STAGE_B3(4, T + 1, nb); STAGE_B3(5, T + 1, nb); }
        BARF();
        PRIO1; MFMA_P3(2); PRIO0;
        if (pf) WAITV(4);
        BARF();
    }

    float bv[6];
#pragma unroll
    for (int jj = 0; jj < 6; ++jj) bv[jj] = bias[n0 + wn_idx * 96 + jj * 16 + lr];
#pragma unroll
    for (int ii = 0; ii < 4; ++ii) {
        int row = m0 + wm_idx * 64 + ii * 16 + lh * 4;
#pragma unroll
        for (int jj = 0; jj < 6; ++jj) {
            int col = n0 + wn_idx * 96 + jj * 16 + lr;
#pragma unroll
            for (int r = 0; r < 4; ++r) {
                float v = acc[ii][jj][r] + bv[jj];
                C[(size_t)(row + r) * N + col] = f2bf(v);
            }
        }
    }
}

// ================= fused RoPE q/k (vectorized) + V transpose (1 launch) =================
// RoPE branch: 16 threads per 128-dim head vector, 4 rotation pairs per thread.
// Loads 16B short8 (16-lane groups read contiguous 256B; consecutive h -> contiguous 1KB
// per wave), 2x16B table reads (L2-hot), 2x8B stores. Same per-element math/rounding
// as the scalar version -> bit-identical output.
__global__ void rope_v_fused(const ushort* __restrict__ qkv, const float2* __restrict__ tab,
                             ushort* __restrict__ Qb, ushort* __restrict__ Kb,
                             ushort* __restrict__ Vt) {
    __shared__ ushort tile[32][33];
    int blk = blockIdx.x;
    int t = threadIdx.x;
    if (blk < 8192) {
        int gid = blk * 256 + t;      // 0..2097151
        int v = gid >> 4;             // head-vector id, 0..131071
        int jt = gid & 15;            // pair-quad id, pairs 4jt..4jt+3
        int bs = v >> 5;
        int rem = v & 31;
        int which = rem >> 4;  // 0=q, 1=k
        int h = rem & 15;
        int s = bs & 2047;
        int b = bs >> 11;
        size_t src = (size_t)bs * QKV_LD + which * D_MODEL + h * HD + 8 * jt;
        short8 in8 = *(const short8*)(qkv + src);
        float4 t01 = *(const float4*)(tab + (s << 6) + 4 * jt);     // cs0,sn0,cs1,sn1
        float4 t23 = *(const float4*)(tab + (s << 6) + 4 * jt + 2); // cs2,sn2,cs3,sn3
        float sc = which ? 1.0f : 0.08838834764831845f; // fold 1/sqrt(128) into Q
        float cs[4] = { t01.x, t01.z, t23.x, t23.z };
        float sn[4] = { t01.y, t01.w, t23.y, t23.w };
        ushort4 o1, o2;
        {
            float x1, x2, a, bv_;
            x1 = bf2f((ushort)in8[0]); x2 = bf2f((ushort)in8[1]);
            a = (x1 * cs[0] - x2 * sn[0]) * sc; bv_ = (x1 * sn[0] + x2 * cs[0]) * sc;
            o1.x = f2bf(a); o2.x = f2bf(bv_);
            x1 = bf2f((ushort)in8[2]); x2 = bf2f((ushort)in8[3]);
            a = (x1 * cs[1] - x2 * sn[1]) * sc; bv_ = (x1 * sn[1] + x2 * cs[1]) * sc;
            o1.y = f2bf(a); o2.y = f2bf(bv_);
            x1 = bf2f((ushort)in8[4]); x2 = bf2f((ushort)in8[5]);
            a = (x1 * cs[2] - x2 * sn[2]) * sc; bv_ = (x1 * sn[2] + x2 * cs[2]) * sc;
            o1.z = f2bf(a); o2.z = f2bf(bv_);
            x1 = bf2f((ushort)in8[6]); x2 = bf2f((ushort)in8[7]);
            a = (x1 * cs[3] - x2 * sn[3]) * sc; bv_ = (x1 * sn[3] + x2 * cs[3]) * sc;
            o1.w = f2bf(a); o2.w = f2bf(bv_);
        }
        ushort* dst = which ? Kb : Qb;
        size_t obase = ((size_t)(b * NH + h) * SEQ + s) * HD;
        *(ushort4*)(dst + obase + 4 * jt) = o1;
        *(ushort4*)(dst + obase + 64 + 4 * jt) = o2;
    } else {
        // V transpose -> Vt [bh][d=128][s=2048]; grid (64,4,32) flattened
        int i = blk - 8192;
        int bx = i & 63, by = (i >> 6) & 3, bz = i >> 8;
        int tx = t & 31, ty = t >> 5; // 32 x 8
        int s0 = bx * 32;
        int d0 = by * 32;
        int bh = bz;
        int b = bh >> 4, h = bh & 15;
        for (int k = 0; k < 4; ++k) {
            int s = s0 + ty + k * 8;
            tile[ty + k * 8][tx] = qkv[((size_t)(b * SEQ + s)) * QKV_LD + 2 * D_MODEL + h * HD + d0 + tx];
        }
        __syncthreads();
        for (int k = 0; k < 4; ++k) {
            int d = d0 + ty + k * 8;
            Vt[((size_t)bh * HD + d) * SEQ + s0 + tx] = tile[tx][ty + k * 8];
        }
    }
}

// ---------------- MFMA flash attention ----------------
// EXACT R5 hardware-proven body (123.6us @ 20% occupancy, VGPR 124).
// No defer-max, no setprio, no DMA staging, no exp2, f2bf P-pack: all grafts
// measured-regressive on this register-saturated 4-wave body (R8-R12 post-mortems).
// XCD-aware work swizzle (bijective, 512%8==0): all 16 q-tiles of each bh on one XCD.
__global__ __launch_bounds__(256) void attn_mfma(const ushort* __restrict__ Qb,
                                                 const ushort* __restrict__ Kb,
                                                 const ushort* __restrict__ Vt,
                                                 ushort* __restrict__ ctx) {
    __shared__ ushort smem[25600]; // Ks[0,8192) Vts[8192,16384) Ps[16384,25600)
    ushort* Ks = smem;          // [64][128], 16B chunks swizzled: c' = c ^ (row&15)
    ushort* Vts = smem + 8192;  // [128][64], 16B chunks swizzled: c' = c ^ (row&7)
    ushort* Ps = smem + 16384;  // [128][72] (pad 8 => 144B rows, 16B aligned)

    int t = threadIdx.x;
    int w = t >> 6, l = t & 63;
    int l31 = l & 31, g = l >> 5;
    int flat = blockIdx.y * 16 + blockIdx.x;    // launched id, 0..511
    int wid = (flat & 7) * 64 + (flat >> 3);    // work id, XCD-grouped by bh
    int q0 = (wid & 15) * 128;
    int bh = wid >> 4;
    int b = bh >> 4, h = bh & 15;

    int qrow = q0 + w * 32 + l31;
    const ushort* Qg = Qb + ((size_t)bh * SEQ + qrow) * HD;
    short8 qf[8];
#pragma unroll
    for (int kc = 0; kc < 8; kc++)
        qf[kc] = *(const short8*)(Qg + kc * 16 + g * 8);

    f32x16 O[4];
#pragma unroll
    for (int di = 0; di < 4; di++) O[di] = (f32x16)0.0f;
    float m_run = -INFINITY, l_run = 0.0f;

    const ushort* KgB = Kb + (size_t)bh * SEQ * HD;
    const ushort* VtB = Vt + (size_t)bh * HD * SEQ;

    for (int k0 = 0; k0 < SEQ; k0 += 64) {
        __syncthreads();
#pragma unroll
        for (int c2 = 0; c2 < 4; c2++) {
            int f = c2 * 256 + t;
            int r = f >> 4, c = f & 15;
            int cp = c ^ (r & 15);
            uint4 v = *(const uint4*)(KgB + (size_t)(k0 + r) * HD + c * 8);
            *(uint4*)(Ks + r * 128 + cp * 8) = v;
        }
#pragma unroll
        for (int c2 = 0; c2 < 4; c2++) {
            int f = c2 * 256 + t;
            int d = f >> 3, c = f & 7;
            int cp = c ^ (d & 7);
            uint4 v = *(const uint4*)(VtB + (size_t)d * SEQ + k0 + c * 8);
            *(uint4*)(Vts + d * 64 + cp * 8) = v;
        }
        __syncthreads();

        // S^T = K . Q^T : per wave [64 keys][32 q] as 2 tiles of 32x32
        f32x16 St[2];
        St[0] = (f32x16)0.0f;
        St[1] = (f32x16)0.0f;
#pragma unroll
        for (int ki = 0; ki < 2; ki++) {
            int row = ki * 32 + l31;
#pragma unroll
            for (int kc = 0; kc < 8; kc++) {
                int cp = (kc * 2 + g) ^ (row & 15);
                short8 a = *(const short8*)(Ks + row * 128 + cp * 8);
                St[ki] = __builtin_amdgcn_mfma_f32_32x32x16_bf16(a, qf[kc], St[ki], 0, 0, 0);
            }
        }

        // online softmax: this lane's q = q0+w*32+l31; keys live in regs
        float mx = -INFINITY;
#pragma unroll
        for (int ki = 0; ki < 2; ki++)
#pragma unroll
            for (int r = 0; r < 16; r++) mx = fmaxf(mx, St[ki][r]);
        mx = fmaxf(mx, __shfl_xor(mx, 32));
        float mn = fmaxf(m_run, mx);
        float alpha = __expf(m_run - mn);
        m_run = mn;
        float psum = 0.0f;
#pragma unroll
        for (int ki = 0; ki < 2; ki++)
#pragma unroll
            for (int r = 0; r < 16; r++) {
                float p = __expf(St[ki][r] - mn);
                St[ki][r] = p;
                psum += p;
            }
        psum += __shfl_xor(psum, 32);
        l_run = l_run * alpha + psum;
#pragma unroll
        for (int di = 0; di < 4; di++)
#pragma unroll
            for (int r = 0; r < 16; r++) O[di][r] *= alpha;

        // P (bf16) -> LDS, wave-private rows; reg-quads = 4 consecutive keys => b64 writes
        {
            int qloc = w * 32 + l31;
            ushort* Pr = Ps + qloc * 72;
#pragma unroll
            for (int ki = 0; ki < 2; ki++)
#pragma unroll
                for (int u = 0; u < 4; u++) {
                    ushort4 pk;
                    pk.x = f2bf(St[ki][4 * u + 0]);
                    pk.y = f2bf(St[ki][4 * u + 1]);
                    pk.z = f2bf(St[ki][4 * u + 2]);
                    pk.w = f2bf(St[ki][4 * u + 3]);
                    *(ushort4*)(Pr + ki * 32 + 8 * u + 4 * g) = pk;
                }
        }

        // O^T += V^T . P^T : per wave [128 d][32 q] as 4 tiles of 32x32
        {
            int qloc = w * 32 + l31;
            short8 pb[4];
#pragma unroll
            for (int kc = 0; kc < 4; kc++)
                pb[kc] = *(const short8*)(Ps + qloc * 72 + kc * 16 + g * 8);
#pragma unroll
            for (int di = 0; di < 4; di++) {
                int d = di * 32 + l31;
#pragma unroll
                for (int kc = 0; kc < 4; kc++) {
                    int cp = (kc * 2 + g) ^ (d & 7);
                    short8 va = *(const short8*)(Vts + d * 64 + cp * 8);
                    O[di] = __builtin_amdgcn_mfma_f32_32x32x16_bf16(va, pb[kc], O[di], 0, 0, 0);
                }
            }
        }
    }

    __syncthreads();
    float inv = 1.0f / l_run;
    ushort* ob = smem; // [128][128] rows = block-local q
    {
        int qloc = w * 32 + l31;
        ushort* orow = ob + qloc * 128;
#pragma unroll
        for (int di = 0; di < 4; di++)
#pragma unroll
            for (int u = 0; u < 4; u++) {
                ushort4 pk;
                pk.x = f2bf(O[di][4 * u + 0] * inv);
                pk.y = f2bf(O[di][4 * u + 1] * inv);
                pk.z = f2bf(O[di][4 * u + 2] * inv);
                pk.w = f2bf(O[di][4 * u + 3] * inv);
                *(ushort4*)(orow + di * 32 + 8 * u + 4 * g) = pk;
            }
    }
#pragma unroll
    for (int p = 0; p < 8; p++) {
        int qloc = w * 32 + p * 4 + (l >> 4);
        int c16 = l & 15;
        uint4 v = *(const uint4*)(ob + qloc * 128 + c16 * 8);
        size_t tok = (size_t)b * SEQ + q0 + qloc;
        *(uint4*)(ctx + tok * D_MODEL + h * HD + c16 * 8) = v;
    }
}

extern "C" void kernel_launch(void* const* d_in, const int* in_sizes, int n_in,
                              void* d_out, int out_size, void* d_ws, size_t ws_size,
                              hipStream_t stream) {
    const float* x    = (const float*)d_in[0];
    const float* Wqkv = (const float*)d_in[1];
    const float* bqkv = (const float*)d_in[2];
    const float* Wo   = (const float*)d_in[3];
    const float* bo   = (const float*)d_in[4];
    float* out = (float*)d_out;

    char* ws = (char*)d_ws;
    ushort* x_bf   = (ushort*)(ws);                  // 16 MB [0,16M)
    ushort* wqkvT  = (ushort*)(ws + 16777216);       // 24 MB
    ushort* woT    = (ushort*)(ws + 41943040);       //  8 MB
    ushort* qkv_bf = (ushort*)(ws + 50331648);       // 48 MB: [4096][6144] bf16
    ushort* Qb     = (ushort*)(ws + 100663296);      // 16 MB: [32][2048][128] bf16
    ushort* Kb     = (ushort*)(ws + 117440512);      // 16 MB
    ushort* VtG    = (ushort*)(ws + 134217728);      // 16 MB: [32][128][2048] bf16
    ushort* ctx    = (ushort*)(ws + 150994944);      // 16 MB -> total 160 MB
    // rope table overlaps ctx region (1 MB): consumed by rope_v_fused BEFORE attn writes ctx.
    float2* rtab   = (float2*)(ws + 150994944);

    // 1) fused prep: rope table + x->bf16 + Wqkv^T + Wo^T
    prep_fused<<<25088, 256, 0, stream>>>(x, x_bf, Wqkv, wqkvT, Wo, woT, rtab);
    // 2) qkv = x @ Wqkv + bqkv -> bf16 (128x384, 512 blocks = 2 exact rounds)
    gemm384<<<dim3(16, 32), 512, 0, stream>>>(x_bf, wqkvT, bqkv, qkv_bf, 4096, 6144, 2048);
    // 3) fused RoPE q/k (vectorized, 16 thr/vector) + V transpose
    rope_v_fused<<<16384, 256, 0, stream>>>(qkv_bf, rtab, Qb, Kb, VtG);
    // 4) MFMA flash attention -> ctx bf16 (XCD-swizzled, R5-proven body)
    attn_mfma<<<dim3(16, 32), 256, 0, stream>>>(Qb, Kb, VtG, ctx);
    // 5) out = ctx @ Wo + bo (256x128, 256 blocks = full machine)
    gemm256<float, 1><<<dim3(16, 16), 512, 0, stream>>>(ctx, woT, bo, out, 4096, 2048, 2048);
}